// Round 14
// baseline (124.854 us; speedup 1.0000x reference)
//
#include <hip/hip_runtime.h>
#include <cmath>

// Static problem config (matches reference)
#define RB 20
#define RA 19
#define NPT (RB*RA)
#define DZ 25
#define DIN 9
#define MULT 128
#define CH 128

// ---------------------------------------------------------------------------
// Host: transposed dense real-Gaunt table Gt[d1*9+d2][28] in fp64 from the
// reference's own quadrature (exact bilinear identity). Cols 25..27 zero pads.
static void host_build_gaunt(float* out /* 81*28, zero-padded */) {
    const double PI = 3.14159265358979323846;
    double xq[RB], wq[RB];
    for (int i = 0; i < RB; ++i) {
        double x = cos(PI * (i + 0.75) / (RB + 0.5));
        double dp = 0.0;
        for (int it = 0; it < 100; ++it) {
            double p0 = 1.0, p1 = x;
            for (int k = 2; k <= RB; ++k) {
                double p2 = ((2.0*k - 1.0)*x*p1 - (k - 1.0)*p0) / (double)k;
                p0 = p1; p1 = p2;
            }
            dp = RB * (x*p1 - p0) / (x*x - 1.0);
            double dx = p1 / dp;
            x -= dx;
            if (fabs(dx) < 1e-15) break;
        }
        {
            double p0 = 1.0, p1 = x;
            for (int k = 2; k <= RB; ++k) {
                double p2 = ((2.0*k - 1.0)*x*p1 - (k - 1.0)*p0) / (double)k;
                p0 = p1; p1 = p2;
            }
            dp = RB * (x*p1 - p0) / (x*x - 1.0);
        }
        xq[i] = x;
        wq[i] = 2.0 / ((1.0 - x*x)*dp*dp);
    }
    static double Y[DZ][NPT];
    static double qws[NPT];
    for (int b = 0; b < RB; ++b) {
        double ct = xq[b], st = sqrt(fmax(0.0, 1.0 - ct*ct));
        double P[5][5]; double pmm = 1.0;
        for (int m = 0; m <= 4; ++m) {
            if (m > 0) pmm *= -(2.0*m - 1.0) * st;
            P[m][m] = pmm;
            if (m < 4) {
                double pp = pmm, pc = ct*(2.0*m + 1.0)*pmm;
                P[m+1][m] = pc;
                for (int l = m + 2; l <= 4; ++l) {
                    double pn = ((2.0*l - 1.0)*ct*pc - (double)(l + m - 1)*pp) / (double)(l - m);
                    P[l][m] = pn; pp = pc; pc = pn;
                }
            }
        }
        for (int a = 0; a < RA; ++a) {
            int pt = b*RA + a;
            qws[pt] = wq[b] * (2.0*PI/(double)RA);
            double alpha = 2.0*PI*(double)a/(double)RA;
            for (int l = 0; l <= 4; ++l)
                for (int m = -l; m <= l; ++m) {
                    int am = m < 0 ? -m : m;
                    double fr = 1.0;
                    for (int i = l - am + 1; i <= l + am; ++i) fr *= (double)i;
                    double nlm = sqrt((2.0*l + 1.0) / (4.0*PI) / fr);
                    double ang = (m == 0) ? 1.0
                               : (m > 0 ? sqrt(2.0)*cos(am*alpha) : sqrt(2.0)*sin(am*alpha));
                    Y[l*l + l + m][pt] = nlm * P[l][am] * ang;
                }
        }
    }
    for (int pr = 0; pr < 81; ++pr) {
        int d1 = pr / 9, d2 = pr % 9;
        for (int d = 0; d < DZ; ++d) {
            double s = 0.0;
            for (int p = 0; p < NPT; ++p)
                s += Y[d][p] * Y[d1][p] * Y[d2][p] * qws[p];
            out[pr*28 + d] = (float)s;
        }
    }
}

// ---------------------------------------------------------------------------
// Stage D helper: wave owns (node, l-aligned d-range); lane owns e=lane,e+64.
// z read as float4 LDS broadcasts; l compile-time -> wz loads CSE'd.
template<int D0, int ND>
__device__ __forceinline__ void d_tile(const float* sZn, const float* __restrict__ wz,
                                       float* sOutn, int lane) {
    const float s128 = 0.08838834764831845f;
    float acc[ND * 2];
    #pragma unroll
    for (int i = 0; i < ND * 2; ++i) acc[i] = 0.f;
    for (int c0 = 0; c0 < CH; c0 += 4) {
        #pragma unroll
        for (int i = 0; i < ND; ++i) {
            const int d = D0 + i;
            const int l = (d == 0) ? 0 : (d < 4) ? 1 : (d < 9) ? 2 : (d < 16) ? 3 : 4;
            float4 z = *(const float4*)(sZn + d * 128 + c0);      // broadcast b128
            #pragma unroll
            for (int k = 0; k < 4; ++k) {
                float wa = wz[l * 16384 + (c0 + k) * 128 + lane];   // CSE across same-l i
                float wb = wz[l * 16384 + (c0 + k) * 128 + lane + 64];
                float zc = (k == 0) ? z.x : (k == 1) ? z.y : (k == 2) ? z.z : z.w;
                acc[i*2+0] = fmaf(zc, wa, acc[i*2+0]);
                acc[i*2+1] = fmaf(zc, wb, acc[i*2+1]);
            }
        }
    }
    #pragma unroll
    for (int i = 0; i < ND; ++i) {
        sOutn[lane * 25 + D0 + i]        = acc[i*2+0] * s128;
        sOutn[(lane + 64) * 25 + D0 + i] = acc[i*2+1] * s128;
    }
}

// ---------------------------------------------------------------------------
// Fully fused, 2 nodes per block, 512 threads (8 waves): 2 blocks/CU ->
// 16 waves/CU (vs round-13's 8). Same instruction totals, 2x latency hiding.
__global__ __launch_bounds__(512) void gaunt_fused(
    const float* __restrict__ xg, const float* __restrict__ yg,
    const float* __restrict__ wxg, const float* __restrict__ wyg,
    const float* __restrict__ wzg, float* __restrict__ outg,
    const float* __restrict__ gGt) {

    // LDS pool (floats), 17884 = 71536 B (2 blocks/CU on 160 KB):
    //  sG   [0,     2268)  Gaunt table (live: start -> C)
    //  sXY  [2268,  6876)  x,y transposed [side][n][d*128+m] (A -> B)
    //  sXc  [6876, 11484)  xc [(side*9+d)*2+n][c] (B -> C-start)
    //  sZ   [11484,17884)  z [n*25+dz][c] (C -> D)
    //  sOut [2268,  8668)  out [n][e][25] (D -> E; aliases dead sXY/sXc-head)
    __shared__ __align__(16) float pool[17884];
    float* sG   = pool;
    float* sXY  = pool + 2268;
    float* sXc  = pool + 6876;
    float* sZ   = pool + 11484;
    float* sOut = pool + 2268;

    const int tid  = threadIdx.x;
    const int b    = blockIdx.x;
    const int lane = tid & 63;
    const int wv   = __builtin_amdgcn_readfirstlane(tid >> 6);   // 0..7
    const float s128 = 0.08838834764831845f;   // 1/sqrt(128)

    // Stage A: G -> LDS; x,y (2 nodes) -> LDS transposed [side][n][d*128+m]
    for (int i = tid; i < 81 * 28; i += 512) sG[i] = gGt[i];
    {
        const float4* xs = (const float4*)(xg + 2 * b * 1152);
        const float4* ys = (const float4*)(yg + 2 * b * 1152);
        for (int i = tid; i < 1152; i += 512) {
            float4 v = (i < 576) ? xs[i] : ys[i - 576];
            int r = (i < 576) ? i : i - 576;
            int base = (i < 576) ? 0 : 2304;
            int j0 = r * 4;
            #pragma unroll
            for (int k = 0; k < 4; ++k) {
                int j = j0 + k;
                int n = j / 1152;
                int jj = j - n * 1152;
                int m = jj / 9, d = jj - 9 * m;
                float val = (k == 0) ? v.x : (k == 1) ? v.y : (k == 2) ? v.z : v.w;
                sXY[base + n * 1152 + d * 128 + m] = val;
            }
        }
    }
    __syncthreads();

    // Stage B: linear_in. wave=(side, c-quarter); lane=(c mod 32, node).
    {
        const int side = wv >> 2;
        const int cq = wv & 3;
        const int c = cq * 32 + (lane & 31);
        const int n = lane >> 5;
        const float* wb = side ? wyg : wxg;
        const float* xb = sXY + side * 2304 + n * 1152;   // [d*128+m]
        float acc[9];
        #pragma unroll
        for (int d = 0; d < 9; ++d) acc[d] = 0.f;
        for (int m0 = 0; m0 < MULT; m0 += 4) {
            float w0[4], w1[4], w2[4];
            #pragma unroll
            for (int k = 0; k < 4; ++k) {
                w0[k] = wb[(m0 + k) * 128 + c];
                w1[k] = wb[16384 + (m0 + k) * 128 + c];
                w2[k] = wb[32768 + (m0 + k) * 128 + c];
            }
            #pragma unroll
            for (int d = 0; d < 9; ++d) {
                const float* wl = (d == 0) ? w0 : (d < 4) ? w1 : w2;
                float4 xv = *(const float4*)(xb + d * 128 + m0);  // 2-addr/wave, free
                acc[d] = fmaf(xv.x, wl[0], acc[d]);
                acc[d] = fmaf(xv.y, wl[1], acc[d]);
                acc[d] = fmaf(xv.z, wl[2], acc[d]);
                acc[d] = fmaf(xv.w, wl[3], acc[d]);
            }
        }
        #pragma unroll
        for (int d = 0; d < 9; ++d)
            sXc[((side * 9 + d) * 2 + n) * 128 + c] = acc[d] * s128;
    }
    __syncthreads();

    // Stage C: thread=(c, node, dz-half); dense G contraction, b128 G reads.
    {
        const int c = tid & 127;
        const int n = (tid >> 7) & 1;
        const int half = __builtin_amdgcn_readfirstlane(tid >> 8);
        const int dz0 = half ? 12 : 0;
        float xr[9], yr[9];
        #pragma unroll
        for (int d = 0; d < 9; ++d) {
            xr[d] = sXc[(d * 2 + n) * 128 + c];
            yr[d] = sXc[((9 + d) * 2 + n) * 128 + c];
        }
        float a[13];
        #pragma unroll
        for (int i = 0; i < 13; ++i) a[i] = 0.f;
        for (int d1 = 0; d1 < 9; ++d1) {
            #pragma unroll
            for (int d2 = 0; d2 < 9; ++d2) {
                float p = xr[d1] * yr[d2];
                const float* gt = sG + (d1 * 9 + d2) * 28 + dz0;   // 16B-aligned
                float4 g0 = *(const float4*)gt;
                float4 g1 = *(const float4*)(gt + 4);
                float4 g2 = *(const float4*)(gt + 8);
                float  g3 = gt[12];
                float gv[13] = {g0.x,g0.y,g0.z,g0.w, g1.x,g1.y,g1.z,g1.w,
                                g2.x,g2.y,g2.z,g2.w, g3};
                #pragma unroll
                for (int i = 0; i < 13; ++i) a[i] = fmaf(p, gv[i], a[i]);
            }
        }
        float* zn = sZ + n * 25 * 128;
        if (half == 0) {
            #pragma unroll
            for (int i = 0; i < 12; ++i) zn[i * 128 + c] = a[i];    // dz 0..11
        } else {
            #pragma unroll
            for (int i = 0; i < 13; ++i) zn[(12 + i) * 128 + c] = a[i];  // dz 12..24
        }
    }
    __syncthreads();   // sZ ready; sXY/sXc/sG dead -> sOut may alias

    // Stage D: wave=(node, l-range); wz_l read once per node-group.
    {
        const int n = wv >> 2;
        const int dr = wv & 3;
        const float* zn = sZ + n * 25 * 128;
        float* on = sOut + n * 3200;
        if      (dr == 0) d_tile<0, 4>(zn, wzg, on, lane);   // l0+l1
        else if (dr == 1) d_tile<4, 5>(zn, wzg, on, lane);   // l2
        else if (dr == 2) d_tile<9, 7>(zn, wzg, on, lane);   // l3
        else              d_tile<16, 9>(zn, wzg, on, lane);  // l4
    }
    __syncthreads();

    // Stage E: coalesced float4 store of both nodes' outputs
    float* po = outg + 2 * b * (CH * DZ);
    const float4* so = (const float4*)sOut;
    for (int j = tid; j < (2 * CH * DZ) / 4; j += 512)
        ((float4*)po)[j] = so[j];
}

extern "C" void kernel_launch(void* const* d_in, const int* in_sizes, int n_in,
                              void* d_out, int out_size, void* d_ws, size_t ws_size,
                              hipStream_t stream) {
    static float h_gGt[81 * 28];   // zero-init pads
    host_build_gaunt(h_gGt);
    hipMemcpyAsync(d_ws, h_gGt, sizeof(h_gGt), hipMemcpyHostToDevice, stream);

    int N = in_sizes[0] / (MULT * DIN);

    hipLaunchKernelGGL(gaunt_fused, dim3(N / 2), dim3(512), 0, stream,
                       (const float*)d_in[0], (const float*)d_in[1],
                       (const float*)d_in[2], (const float*)d_in[3],
                       (const float*)d_in[4], (float*)d_out, (const float*)d_ws);
}